// Round 3
// baseline (176.843 us; speedup 1.0000x reference)
//
#include <hip/hip_runtime.h>

// out[n][p][m] = sum_c x[n][c][p] * rm[n][c][m]
// N=16, C=64, P=65536, M=128. Memory-bound: 256MB read + 512MB write -> floor ~122us.
// v3: double-buffered x tile (1 barrier/tile), conflict-free XOR-swizzled gather,
//     2-deep read prefetch, nontemporal output stores. rm staging unioned into buf[1].

#define NB   16
#define CDIM 64
#define PDIM 65536
#define MDIM 128
#define PT   128
#define BLOCKS_PER_N 64
#define TILES 8
#define XS   132   // lds_x row stride in bf16 elems (264B rows)

typedef __attribute__((ext_vector_type(8))) short bf16x8;
typedef __attribute__((ext_vector_type(4))) float f32x4;

__device__ __forceinline__ unsigned short f2bf(float f) {
  union { float f; unsigned int u; } v; v.f = f;
  unsigned int u = v.u;
  u += 0x7fffu + ((u >> 16) & 1u);  // RNE
  return (unsigned short)(u >> 16);
}

// rm tile swizzle (verified v1/v2): [m][64c] bf16, 16B-slot XOR
__device__ __forceinline__ int swz(int row, int col) {
  int slot = (col >> 3) ^ (row & 7);
  return row * 64 + slot * 8 + (col & 7);
}

// x tile: [c][p] with p XOR-swizzled by g-group of c -> conflict-free gathers.
// XOR touches only bits >=4 of p, so 4-elem (8B) write chunks stay contiguous.
__device__ __forceinline__ int xswz(int c, int p) {
  return c * XS + (p ^ (((c >> 3) & 3) << 4));
}

__global__ __launch_bounds__(256, 4) void nlsa_kernel(
    const float* __restrict__ x, const float* __restrict__ rm,
    float* __restrict__ out) {
  // buf[1] doubles as the rm staging area (needs 8192 <= 8448 shorts)
  __shared__ unsigned short lds[2][CDIM * XS];   // 33792 B total -> 4 blocks/CU

  const int t = threadIdx.x;
  const int b = blockIdx.x;
  const int n  = b >> 6;
  const int bt = b & 63;

  const float* xn   = x  + (size_t)n * CDIM * PDIM;
  const float* rmn  = rm + (size_t)n * CDIM * MDIM;
  float*       outn = out + (size_t)n * PDIM * MDIM;

  // x staging map: thread t loads float4 at (c = cst+8*it, p = pst..pst+3)
  const int cst = t >> 5;          // 0..7
  const int pst = (t & 31) * 4;    // 0..124

  float4 r[8];
  // issue tile-0 loads first so they fly under rm staging
  {
    const float* src = xn + (size_t)(bt * PT + pst);
#pragma unroll
    for (int it = 0; it < 8; ++it)
      r[it] = *(const float4*)(src + (size_t)(cst + it * 8) * PDIM);
  }

  // ---- stage rm[n] -> lds[1] as [m][c] bf16 (once per block)
  {
    const int m  = t & 127;
    const int cb = (t >> 7) * 4;
#pragma unroll
    for (int it = 0; it < 8; ++it) {
      const int c0 = cb + it * 8;
      ushort4 v;
      v.x = f2bf(rmn[(c0 + 0) * MDIM + m]);
      v.y = f2bf(rmn[(c0 + 1) * MDIM + m]);
      v.z = f2bf(rmn[(c0 + 2) * MDIM + m]);
      v.w = f2bf(rmn[(c0 + 3) * MDIM + m]);
      *(ushort4*)&lds[1][swz(m, c0)] = v;
    }
  }
  __syncthreads();

  const int w  = t >> 6;    // wave: m range [32w, 32w+32)
  const int l  = t & 63;
  const int lo = l & 15;
  const int g  = l >> 4;

  // A fragments (rm) in registers for the whole kernel (read from lds[1])
  bf16x8 a[2][2];
#pragma unroll
  for (int mt = 0; mt < 2; ++mt)
#pragma unroll
    for (int ks = 0; ks < 2; ++ks)
      a[mt][ks] = *(const bf16x8*)&lds[1][swz(w * 32 + mt * 16 + lo,
                                              ks * 32 + g * 8)];

  // ---- write tile 0 -> lds[0]  (waits counted vmcnt for r)
#pragma unroll
  for (int it = 0; it < 8; ++it) {
    ushort4 v;
    v.x = f2bf(r[it].x); v.y = f2bf(r[it].y);
    v.z = f2bf(r[it].z); v.w = f2bf(r[it].w);
    *(ushort4*)&lds[0][xswz(cst + it * 8, pst)] = v;
  }
  // issue tile-1 loads
  {
    const float* src = xn + (size_t)((bt + BLOCKS_PER_N) * PT + pst);
#pragma unroll
    for (int it = 0; it < 8; ++it)
      r[it] = *(const float4*)(src + (size_t)(cst + it * 8) * PDIM);
  }

  // barrier: lds[0] tile ready, lds[1] A-frag reads drained (lgkm-only, no
  // store/vm drain)
  asm volatile("s_waitcnt lgkmcnt(0)" ::: "memory");
  __builtin_amdgcn_s_barrier();
  asm volatile("" ::: "memory");

  for (int k = 0; k < TILES; ++k) {
    unsigned short* cur = lds[k & 1];
    unsigned short* nxt = lds[(k + 1) & 1];

    // ds_write tile k+1 (in r) -> nxt; overlaps with compute below
    if (k + 1 < TILES) {
#pragma unroll
      for (int it = 0; it < 8; ++it) {
        ushort4 v;
        v.x = f2bf(r[it].x); v.y = f2bf(r[it].y);
        v.z = f2bf(r[it].z); v.w = f2bf(r[it].w);
        *(ushort4*)&nxt[xswz(cst + it * 8, pst)] = v;
      }
      // issue loads of tile k+2 (2-deep prefetch)
      if (k + 2 < TILES) {
        const float* src =
            xn + (size_t)((bt + (k + 2) * BLOCKS_PER_N) * PT + pst);
#pragma unroll
        for (int it = 0; it < 8; ++it)
          r[it] = *(const float4*)(src + (size_t)(cst + it * 8) * PDIM);
      }
    }

    // ---- compute tile k from cur
    const int p_base = (bt + k * BLOCKS_PER_N) * PT;
#pragma unroll
    for (int pt_ = 0; pt_ < 8; ++pt_) {
      const int pl  = pt_ * 16 + lo;
      const int pls = pl ^ (g << 4);   // matches xswz for c in group g
      bf16x8 b0, b1;
#pragma unroll
      for (int i = 0; i < 8; ++i) {
        b0[i] = (short)cur[(g * 8 + i) * XS + pls];
        b1[i] = (short)cur[(32 + g * 8 + i) * XS + pls];
      }
      f32x4 acc0 = {0.f, 0.f, 0.f, 0.f};
      f32x4 acc1 = {0.f, 0.f, 0.f, 0.f};
      acc0 = __builtin_amdgcn_mfma_f32_16x16x32_bf16(a[0][0], b0, acc0, 0, 0, 0);
      acc0 = __builtin_amdgcn_mfma_f32_16x16x32_bf16(a[0][1], b1, acc0, 0, 0, 0);
      acc1 = __builtin_amdgcn_mfma_f32_16x16x32_bf16(a[1][0], b0, acc1, 0, 0, 0);
      acc1 = __builtin_amdgcn_mfma_f32_16x16x32_bf16(a[1][1], b1, acc1, 0, 0, 0);

      float* dst = outn + (size_t)(p_base + pl) * MDIM + w * 32 + g * 4;
      __builtin_nontemporal_store(acc0, (f32x4*)(dst));        // m=32w+4g+{0..3}
      __builtin_nontemporal_store(acc1, (f32x4*)(dst + 16));   // +16 m
    }

    // one barrier per tile: lgkm drain covers this iter's ds_writes (nxt) and
    // ds_reads (cur, overwritten next iter). Store queue NOT drained.
    asm volatile("s_waitcnt lgkmcnt(0)" ::: "memory");
    __builtin_amdgcn_s_barrier();
    asm volatile("" ::: "memory");
  }
}

extern "C" void kernel_launch(void* const* d_in, const int* in_sizes, int n_in,
                              void* d_out, int out_size, void* d_ws, size_t ws_size,
                              hipStream_t stream) {
  const float* x  = (const float*)d_in[0];   // (N, C, H, W) fp32
  const float* rm = (const float*)d_in[1];   // (N, C, M) fp32
  float* out = (float*)d_out;                // (N, P, M) fp32
  nlsa_kernel<<<dim3(NB * BLOCKS_PER_N), dim3(256), 0, stream>>>(x, rm, out);
}

// Round 4
// 161.590 us; speedup vs baseline: 1.0944x; 1.0944x over previous
//
#include <hip/hip_runtime.h>

// out[n][p][m] = sum_c x[n][c][p] * rm[n][c][m]
// N=16, C=64, P=65536, M=128. Memory-bound: 256MB read + 512MB write -> floor ~122us.
// v4 = v2 (161.7us) + conflict-free XOR-swizzled gather ONLY.
//      (v3's nt-stores/double-buffer reverted -- regressed to 176.8us)

#define NB   16
#define CDIM 64
#define PDIM 65536
#define MDIM 128
#define PT   128
#define BLOCKS_PER_N 64
#define TILES_PER_BLOCK 8
#define XS   132   // lds_x row stride (bf16)

typedef __attribute__((ext_vector_type(8))) short bf16x8;
typedef __attribute__((ext_vector_type(4))) float f32x4;

__device__ __forceinline__ unsigned short f2bf(float f) {
  union { float f; unsigned int u; } v; v.f = f;
  unsigned int u = v.u;
  u += 0x7fffu + ((u >> 16) & 1u);  // RNE
  return (unsigned short)(u >> 16);
}

// rm tile swizzle (verified): [m][64c] bf16, 16B-slot XOR
__device__ __forceinline__ int swz(int row, int col) {
  int slot = (col >> 3) ^ (row & 7);
  return row * 64 + slot * 8 + (col & 7);
}

// x tile: [c][p], p XOR-swizzled by c-group -> per-fragment bank starts
// {0,8,16,24}+2i : exact 32-bank tiling, 2 lanes/bank (free). XOR touches only
// p bits 4-5, so 4-elem (8B) write chunks stay contiguous and in-row.
__device__ __forceinline__ int xswz(int c, int p) {
  return c * XS + (p ^ (((c >> 3) & 3) << 4));
}

__global__ __launch_bounds__(256, 4) void nlsa_kernel(
    const float* __restrict__ x, const float* __restrict__ rm,
    float* __restrict__ out) {
  __shared__ unsigned short lds_rm[MDIM * CDIM];  // 16KB
  __shared__ unsigned short lds_x[CDIM * XS];     // 16.5KB

  const int t = threadIdx.x;
  const int b = blockIdx.x;
  const int n  = b >> 6;
  const int bt = b & 63;

  const float* xn   = x  + (size_t)n * CDIM * PDIM;
  const float* rmn  = rm + (size_t)n * CDIM * MDIM;
  float*       outn = out + (size_t)n * PDIM * MDIM;

  const int cst = t >> 5;          // 0..7
  const int pst = (t & 31) * 4;    // 0..124

  float4 r[8];
  {
    const float* src = xn + (size_t)(bt * PT + pst);
#pragma unroll
    for (int it = 0; it < 8; ++it)
      r[it] = *(const float4*)(src + (size_t)(cst + it * 8) * PDIM);
  }

  // ---- stage rm[n] -> lds_rm[m][c] bf16 (once per block)
  {
    const int m  = t & 127;
    const int cb = (t >> 7) * 4;
#pragma unroll
    for (int it = 0; it < 8; ++it) {
      const int c0 = cb + it * 8;
      ushort4 v;
      v.x = f2bf(rmn[(c0 + 0) * MDIM + m]);
      v.y = f2bf(rmn[(c0 + 1) * MDIM + m]);
      v.z = f2bf(rmn[(c0 + 2) * MDIM + m]);
      v.w = f2bf(rmn[(c0 + 3) * MDIM + m]);
      *(ushort4*)&lds_rm[swz(m, c0)] = v;
    }
  }
  __syncthreads();

  const int w  = t >> 6;    // wave: m range [32w, 32w+32)
  const int l  = t & 63;
  const int lo = l & 15;
  const int g  = l >> 4;

  // A fragments (rm) in registers for the whole kernel
  bf16x8 a[2][2];
#pragma unroll
  for (int mt = 0; mt < 2; ++mt)
#pragma unroll
    for (int ks = 0; ks < 2; ++ks)
      a[mt][ks] = *(const bf16x8*)&lds_rm[swz(w * 32 + mt * 16 + lo,
                                              ks * 32 + g * 8)];

  for (int k = 0; k < TILES_PER_BLOCK; ++k) {
    // barrier1: all waves done reading lds_x for tile k-1 (reads consumed
    // pre-barrier) -- raw barrier, no vm/store drain.
    asm volatile("" ::: "memory");
    __builtin_amdgcn_s_barrier();
    asm volatile("" ::: "memory");

    // write staged tile into lds_x (compiler inserts counted vmcnt for r)
#pragma unroll
    for (int it = 0; it < 8; ++it) {
      ushort4 v;
      v.x = f2bf(r[it].x); v.y = f2bf(r[it].y);
      v.z = f2bf(r[it].z); v.w = f2bf(r[it].w);
      *(ushort4*)&lds_x[xswz(cst + it * 8, pst)] = v;
    }

    // prefetch tile k+1 into r (overlaps the compute phase below)
    if (k + 1 < TILES_PER_BLOCK) {
      const float* src = xn + (size_t)((bt + (k + 1) * BLOCKS_PER_N) * PT + pst);
#pragma unroll
      for (int it = 0; it < 8; ++it)
        r[it] = *(const float4*)(src + (size_t)(cst + it * 8) * PDIM);
    }

    // barrier2: lds_x writes visible; lgkm-only wait (store queue NOT drained)
    asm volatile("s_waitcnt lgkmcnt(0)" ::: "memory");
    __builtin_amdgcn_s_barrier();
    asm volatile("" ::: "memory");

    const int p_base = (bt + k * BLOCKS_PER_N) * PT;
#pragma unroll
    for (int pt_ = 0; pt_ < 8; ++pt_) {
      const int pl  = pt_ * 16 + lo;
      const int pls = pl ^ (g << 4);   // matches xswz for c-groups g and g+4
      bf16x8 b0, b1;
#pragma unroll
      for (int i = 0; i < 8; ++i) {
        b0[i] = (short)lds_x[(g * 8 + i) * XS + pls];
        b1[i] = (short)lds_x[(32 + g * 8 + i) * XS + pls];
      }
      f32x4 acc0 = {0.f, 0.f, 0.f, 0.f};
      f32x4 acc1 = {0.f, 0.f, 0.f, 0.f};
      acc0 = __builtin_amdgcn_mfma_f32_16x16x32_bf16(a[0][0], b0, acc0, 0, 0, 0);
      acc0 = __builtin_amdgcn_mfma_f32_16x16x32_bf16(a[0][1], b1, acc0, 0, 0, 0);
      acc1 = __builtin_amdgcn_mfma_f32_16x16x32_bf16(a[1][0], b0, acc1, 0, 0, 0);
      acc1 = __builtin_amdgcn_mfma_f32_16x16x32_bf16(a[1][1], b1, acc1, 0, 0, 0);

      float* dst = outn + (size_t)(p_base + pl) * MDIM + w * 32 + g * 4;
      *(f32x4*)(dst)      = acc0;   // m = 32w + 4g + {0..3}
      *(f32x4*)(dst + 16) = acc1;   // m = 32w + 16 + 4g + {0..3}
    }
  }
}

extern "C" void kernel_launch(void* const* d_in, const int* in_sizes, int n_in,
                              void* d_out, int out_size, void* d_ws, size_t ws_size,
                              hipStream_t stream) {
  const float* x  = (const float*)d_in[0];   // (N, C, H, W) fp32
  const float* rm = (const float*)d_in[1];   // (N, C, M) fp32
  float* out = (float*)d_out;                // (N, P, M) fp32
  nlsa_kernel<<<dim3(NB * BLOCKS_PER_N), dim3(256), 0, stream>>>(x, rm, out);
}